// Round 1
// baseline (1702.642 us; speedup 1.0000x reference)
//
#include <hip/hip_runtime.h>

// ---------------- kernels ----------------

__global__ void k_init_cnt(int* cnt, int N) {
    int i = blockIdx.x * blockDim.x + threadIdx.x;
    if (i < N) cnt[i] = 1;  // 1 = self-loop
}

__global__ void k_hist(const int* dst, int* cnt, int E) {
    int i = blockIdx.x * blockDim.x + threadIdx.x;
    if (i < E) atomicAdd(&cnt[dst[i]], 1);
}

// block scans 1024 elements (256 threads x 4); writes block-local exclusive
// prefix into offs, block total into bsum.
__global__ void k_scan1(const int* cnt, int* offs, int* bsum, int N) {
    __shared__ int lds[256];
    int t = threadIdx.x, b = blockIdx.x;
    int idx = b * 1024 + t * 4;
    int e0 = (idx + 0 < N) ? cnt[idx + 0] : 0;
    int e1 = (idx + 1 < N) ? cnt[idx + 1] : 0;
    int e2 = (idx + 2 < N) ? cnt[idx + 2] : 0;
    int e3 = (idx + 3 < N) ? cnt[idx + 3] : 0;
    int s = e0 + e1 + e2 + e3;
    lds[t] = s;
    __syncthreads();
    for (int off = 1; off < 256; off <<= 1) {
        int v = (t >= off) ? lds[t - off] : 0;
        __syncthreads();
        lds[t] += v;
        __syncthreads();
    }
    int excl = lds[t] - s;
    if (idx + 0 < N) offs[idx + 0] = excl;
    if (idx + 1 < N) offs[idx + 1] = excl + e0;
    if (idx + 2 < N) offs[idx + 2] = excl + e0 + e1;
    if (idx + 3 < N) offs[idx + 3] = excl + e0 + e1 + e2;
    if (t == 0) bsum[b] = lds[255];
}

// single block scans <=256 block sums -> exclusive block offsets
__global__ void k_scan2(const int* bsum, int* boff, int nblk) {
    __shared__ int lds[256];
    int t = threadIdx.x;
    int v = (t < nblk) ? bsum[t] : 0;
    lds[t] = v;
    __syncthreads();
    for (int off = 1; off < 256; off <<= 1) {
        int u = (t >= off) ? lds[t - off] : 0;
        __syncthreads();
        lds[t] += u;
        __syncthreads();
    }
    if (t < nblk) boff[t] = lds[t] - v;
}

__global__ void k_scan3(int* offs, const int* boff, int* cur, int N, int EL) {
    int i = blockIdx.x * blockDim.x + threadIdx.x;
    if (i < N) {
        int v = offs[i] + boff[i >> 10];
        offs[i] = v;
        cur[i]  = v;
    }
    if (i == 0) offs[N] = EL;
}

__global__ void k_dis(const int* cnt, float* dis, int N) {
    int i = blockIdx.x * blockDim.x + threadIdx.x;
    if (i < N) dis[i] = rsqrtf((float)cnt[i]);  // deg >= 1 always (self-loop)
}

// scatter src ids into CSR slots (edges then self-loops)
__global__ void k_fill(const int* ei, int* cur, int* csr, int E, int N) {
    int i = blockIdx.x * blockDim.x + threadIdx.x;
    int total = E + N;
    if (i >= total) return;
    int s, d;
    if (i < E) { s = ei[i]; d = ei[E + i]; }
    else       { s = i - E; d = s; }
    int p = atomicAdd(&cur[d], 1);
    csr[p] = s;
}

// layer-1 scalar aggregation: s1[i] = dis[i] * sum_e dis[src]*x[src]
__global__ void k_agg1(const int* offs, const int* csr, const float* dis,
                       const float* x, float* s1, int N) {
    int i = blockIdx.x * blockDim.x + threadIdx.x;
    if (i >= N) return;
    int b = offs[i], e = offs[i + 1];
    float acc = 0.f;
    for (int k = b; k < e; ++k) {
        int s = csr[k];
        acc += dis[s] * x[s];
    }
    s1[i] = dis[i] * acc;
}

// hw1[i] = relu(s1[i]*Wg1 + bg1) @ Wg2   (4 nodes per 256-thread block)
__global__ void __launch_bounds__(256) k_hw1(const float* s1, const float* Wg1,
                                             const float* bg1, const float* Wg2,
                                             float* hw1, int N) {
    __shared__ float w2[64 * 64];
    __shared__ float h1l[4][64];
    int t = threadIdx.x;
    for (int k = t; k < 64 * 64; k += 256) w2[k] = Wg2[k];
    int nl = t >> 6, l = t & 63;
    int node = blockIdx.x * 4 + nl;
    float h1 = 0.f;
    if (node < N) {
        h1 = s1[node] * Wg1[l] + bg1[l];
        h1 = h1 > 0.f ? h1 : 0.f;
    }
    h1l[nl][l] = h1;
    __syncthreads();
    if (node < N) {
        float acc = 0.f;
        const float* hr = h1l[nl];
        #pragma unroll
        for (int k = 0; k < 64; ++k) acc += hr[k] * w2[k * 64 + l];
        hw1[node * 64 + l] = acc;
    }
}

// layer-2 aggregation: wave per dst node, lane = feature. Then relu + pool.
__global__ void __launch_bounds__(256) k_agg2(const int* offs, const int* csr,
                                              const float* dis, const float* hw1,
                                              const float* bg2, const int* batch,
                                              float* pool, float* cntg, int N) {
    int i = (blockIdx.x * 256 + threadIdx.x) >> 6;  // node = global wave id
    int l = threadIdx.x & 63;
    if (i >= N) return;
    int b = offs[i], e = offs[i + 1];
    float acc = 0.f;
    int k = b;
    for (; k + 2 <= e; k += 2) {
        int sA = csr[k], sB = csr[k + 1];
        float dA = dis[sA], dB = dis[sB];
        acc += dA * hw1[sA * 64 + l];
        acc += dB * hw1[sB * 64 + l];
    }
    if (k < e) {
        int sA = csr[k];
        acc += dis[sA] * hw1[sA * 64 + l];
    }
    float h2 = dis[i] * acc + bg2[l];
    h2 = h2 > 0.f ? h2 : 0.f;
    int g = batch[i];
    atomicAdd(&pool[g * 64 + l], h2);
    if (l == 0) atomicAdd(&cntg[g], 1.0f);
}

// per-graph head: tabular MLP + mean pool + fusion MLP. 64 threads per graph.
__global__ void __launch_bounds__(64) k_head(const float* tabular,
        const float* Wt1, const float* bt1, const float* Wt2, const float* bt2,
        const float* Wf1, const float* bf1, const float* Wf2, const float* bf2,
        const float* pool, const float* cntg, float* out, int TD) {
    __shared__ float tl[128];
    __shared__ float t1[64];
    __shared__ float comb[128];
    __shared__ float f1[64];
    int g = blockIdx.x, l = threadIdx.x;
    for (int k = l; k < TD; k += 64) tl[k] = tabular[g * TD + k];
    __syncthreads();
    float a = bt1[l];
    for (int k = 0; k < TD; ++k) a += tl[k] * Wt1[k * 64 + l];
    t1[l] = a > 0.f ? a : 0.f;
    __syncthreads();
    float b = bt2[l];
    #pragma unroll
    for (int k = 0; k < 64; ++k) b += t1[k] * Wt2[k * 64 + l];
    comb[l] = b;
    float c = cntg[g];
    c = c > 1.f ? c : 1.f;
    comb[64 + l] = pool[g * 64 + l] / c;
    __syncthreads();
    float f = bf1[l];
    for (int k = 0; k < 128; ++k) f += comb[k] * Wf1[k * 64 + l];
    f1[l] = f > 0.f ? f : 0.f;
    __syncthreads();
    if (l < 2) {
        float o = bf2[l];
        #pragma unroll
        for (int k = 0; k < 64; ++k) o += f1[k] * Wf2[k * 2 + l];
        out[g * 2 + l] = o;
    }
}

// ---------------- launcher ----------------

extern "C" void kernel_launch(void* const* d_in, const int* in_sizes, int n_in,
                              void* d_out, int out_size, void* d_ws, size_t ws_size,
                              hipStream_t stream) {
    const float* tabular = (const float*)d_in[0];
    const float* x       = (const float*)d_in[1];
    const int*   ei      = (const int*)d_in[2];
    const int*   batch   = (const int*)d_in[3];
    const float* Wt1 = (const float*)d_in[4];
    const float* bt1 = (const float*)d_in[5];
    const float* Wt2 = (const float*)d_in[6];
    const float* bt2 = (const float*)d_in[7];
    const float* Wg1 = (const float*)d_in[8];
    const float* bg1 = (const float*)d_in[9];
    const float* Wg2 = (const float*)d_in[10];
    const float* bg2 = (const float*)d_in[11];
    const float* Wf1 = (const float*)d_in[12];
    const float* bf1 = (const float*)d_in[13];
    const float* Wf2 = (const float*)d_in[14];
    const float* bf2 = (const float*)d_in[15];

    const int N  = in_sizes[1];
    const int E  = in_sizes[2] / 2;
    const int H  = in_sizes[5];             // 64
    const int TD = in_sizes[4] / H;         // 128
    const int B  = in_sizes[0] / TD;        // 1024
    const int EL = E + N;

    // workspace layout
    char* w = (char*)d_ws;
    size_t off = 0;
    auto alloc = [&](size_t bytes) -> void* {
        void* p = w + off;
        off = (off + bytes + 255) & ~(size_t)255;
        return p;
    };
    int*   cnt  = (int*)alloc((size_t)N * 4);
    int*   offs = (int*)alloc((size_t)(N + 1) * 4);
    int*   cur  = (int*)alloc((size_t)N * 4);
    int*   bsum = (int*)alloc(1024);
    int*   boff = (int*)alloc(1024);
    float* dis  = (float*)alloc((size_t)N * 4);
    float* s1   = (float*)alloc((size_t)N * 4);
    int*   csr  = (int*)alloc((size_t)EL * 4);
    float* hw1  = (float*)alloc((size_t)N * 64 * 4);
    float* pool = (float*)alloc((size_t)B * 64 * 4);
    float* cntg = (float*)alloc((size_t)B * 4);
    (void)ws_size;

    hipMemsetAsync(pool, 0, (size_t)B * 64 * 4, stream);
    hipMemsetAsync(cntg, 0, (size_t)B * 4, stream);

    const int nblk_scan = (N + 1023) / 1024;   // 196 for N=200000 (<=256 ok)

    k_init_cnt<<<(N + 255) / 256, 256, 0, stream>>>(cnt, N);
    k_hist<<<(E + 255) / 256, 256, 0, stream>>>(ei + E, cnt, E);
    k_scan1<<<nblk_scan, 256, 0, stream>>>(cnt, offs, bsum, N);
    k_scan2<<<1, 256, 0, stream>>>(bsum, boff, nblk_scan);
    k_scan3<<<(N + 255) / 256, 256, 0, stream>>>(offs, boff, cur, N, EL);
    k_dis<<<(N + 255) / 256, 256, 0, stream>>>(cnt, dis, N);
    k_fill<<<(EL + 255) / 256, 256, 0, stream>>>(ei, cur, csr, E, N);
    k_agg1<<<(N + 255) / 256, 256, 0, stream>>>(offs, csr, dis, x, s1, N);
    k_hw1<<<(N + 3) / 4, 256, 0, stream>>>(s1, Wg1, bg1, Wg2, hw1, N);
    k_agg2<<<(N + 3) / 4, 256, 0, stream>>>(offs, csr, dis, hw1, bg2, batch,
                                            pool, cntg, N);
    k_head<<<B, 64, 0, stream>>>(tabular, Wt1, bt1, Wt2, bt2,
                                 Wf1, bf1, Wf2, bf2, pool, cntg,
                                 (float*)d_out, TD);
}

// Round 2
// 1302.618 us; speedup vs baseline: 1.3071x; 1.3071x over previous
//
#include <hip/hip_runtime.h>
#include <hip/hip_bf16.h>

// ---------------- kernels ----------------

// cnt starts memset to 0; count in-edges per dst (self-loops added later as +1)
__global__ void k_hist(const int* dst, int* cnt, int E) {
    int i = blockIdx.x * blockDim.x + threadIdx.x;
    if (i < E) atomicAdd(&cnt[dst[i]], 1);
}

// block scans 1024 elements (256 threads x 4) of deg = cnt+1 (self-loop);
// writes block-local exclusive prefix into offs, block total into bsum.
__global__ void k_scan1(const int* cnt, int* offs, int* bsum, int N) {
    __shared__ int lds[256];
    int t = threadIdx.x, b = blockIdx.x;
    int idx = b * 1024 + t * 4;
    int e0 = (idx + 0 < N) ? cnt[idx + 0] + 1 : 0;
    int e1 = (idx + 1 < N) ? cnt[idx + 1] + 1 : 0;
    int e2 = (idx + 2 < N) ? cnt[idx + 2] + 1 : 0;
    int e3 = (idx + 3 < N) ? cnt[idx + 3] + 1 : 0;
    int s = e0 + e1 + e2 + e3;
    lds[t] = s;
    __syncthreads();
    for (int off = 1; off < 256; off <<= 1) {
        int v = (t >= off) ? lds[t - off] : 0;
        __syncthreads();
        lds[t] += v;
        __syncthreads();
    }
    int excl = lds[t] - s;
    if (idx + 0 < N) offs[idx + 0] = excl;
    if (idx + 1 < N) offs[idx + 1] = excl + e0;
    if (idx + 2 < N) offs[idx + 2] = excl + e0 + e1;
    if (idx + 3 < N) offs[idx + 3] = excl + e0 + e1 + e2;
    if (t == 0) bsum[b] = lds[255];
}

// single block scans <=256 block sums -> exclusive block offsets
__global__ void k_scan2(const int* bsum, int* boff, int nblk) {
    __shared__ int lds[256];
    int t = threadIdx.x;
    int v = (t < nblk) ? bsum[t] : 0;
    lds[t] = v;
    __syncthreads();
    for (int off = 1; off < 256; off <<= 1) {
        int u = (t >= off) ? lds[t - off] : 0;
        __syncthreads();
        lds[t] += u;
        __syncthreads();
    }
    if (t < nblk) boff[t] = lds[t] - v;
}

// finalize offsets; also dis = rsqrt(deg), dx = dis*x (fused)
__global__ void k_scan3(int* offs, const int* boff, int* cur, const int* cnt,
                        const float* x, float* dis, float* dx, int N, int EL) {
    int i = blockIdx.x * blockDim.x + threadIdx.x;
    if (i < N) {
        int v = offs[i] + boff[i >> 10];
        offs[i] = v;
        cur[i]  = v;
        float d = rsqrtf((float)(cnt[i] + 1));
        dis[i] = d;
        dx[i]  = d * x[i];
    }
    if (i == 0) offs[N] = EL;
}

// scatter src ids into CSR slots (edges then self-loops)
__global__ void k_fill(const int* ei, int* cur, int* csr, int E, int N) {
    int i = blockIdx.x * blockDim.x + threadIdx.x;
    int total = E + N;
    if (i >= total) return;
    int s, d;
    if (i < E) { s = ei[i]; d = ei[E + i]; }
    else       { s = i - E; d = s; }
    int p = atomicAdd(&cur[d], 1);
    csr[p] = s;
}

// layer-1 scalar aggregation: s1[i] = dis[i] * sum_e dx[src]
__global__ void k_agg1(const int* offs, const int* csr, const float* dx,
                       const float* dis, float* s1, int N) {
    int i = blockIdx.x * blockDim.x + threadIdx.x;
    if (i >= N) return;
    int b = offs[i], e = offs[i + 1];
    float acc = 0.f;
    int k = b;
    for (; k + 4 <= e; k += 4) {
        int s0 = csr[k], s1_ = csr[k + 1], s2 = csr[k + 2], s3 = csr[k + 3];
        float v0 = dx[s0], v1 = dx[s1_], v2 = dx[s2], v3 = dx[s3];
        acc += (v0 + v1) + (v2 + v3);
    }
    for (; k < e; ++k) acc += dx[csr[k]];
    s1[i] = dis[i] * acc;
}

// hw1b[i] = bf16( dis[i] * (relu(s1[i]*Wg1 + bg1) @ Wg2) )
// 16 nodes per 256-thread block (4 at a time), Wg2 staged once in LDS.
__global__ void __launch_bounds__(256) k_hw1(const float* s1, const float* dis,
                                             const float* Wg1, const float* bg1,
                                             const float* Wg2,
                                             __hip_bfloat16* hw1b, int N) {
    __shared__ float w2[64 * 64];
    __shared__ float h1l[4][64];
    int t = threadIdx.x;
    for (int k = t; k < 64 * 64; k += 256) w2[k] = Wg2[k];
    int nl = t >> 6, l = t & 63;
    int base = blockIdx.x * 16;
    for (int g = 0; g < 4; ++g) {
        int node = base + g * 4 + nl;
        float h1 = 0.f;
        float sv = 0.f;
        if (node < N) {
            sv = s1[node];
            h1 = fmaxf(fmaf(sv, Wg1[l], bg1[l]), 0.f);
        }
        __syncthreads();
        h1l[nl][l] = h1;
        __syncthreads();
        if (node < N) {
            float acc = 0.f;
            const float* hr = h1l[nl];
            #pragma unroll
            for (int k = 0; k < 64; ++k) acc += hr[k] * w2[k * 64 + l];
            hw1b[node * 64 + l] = __float2bfloat16(dis[node] * acc);
        }
    }
}

// layer-2 aggregation: wave per dst node, lane = feature; dis[src] pre-folded.
__global__ void __launch_bounds__(256) k_agg2(const int* offs, const int* csr,
                                              const __hip_bfloat16* hw1b,
                                              const float* dis, const float* bg2,
                                              const int* batch, float* pool, int N) {
    int i = (blockIdx.x * 256 + threadIdx.x) >> 6;  // node = global wave id
    int l = threadIdx.x & 63;
    if (i >= N) return;
    int b = offs[i], e = offs[i + 1];
    float acc = 0.f;
    int k = b;
    for (; k + 4 <= e; k += 4) {
        int s0 = csr[k], s1 = csr[k + 1], s2 = csr[k + 2], s3 = csr[k + 3];
        float v0 = __bfloat162float(hw1b[s0 * 64 + l]);
        float v1 = __bfloat162float(hw1b[s1 * 64 + l]);
        float v2 = __bfloat162float(hw1b[s2 * 64 + l]);
        float v3 = __bfloat162float(hw1b[s3 * 64 + l]);
        acc += (v0 + v1) + (v2 + v3);
    }
    for (; k < e; ++k) acc += __bfloat162float(hw1b[csr[k] * 64 + l]);
    float h2 = fmaxf(fmaf(dis[i], acc, bg2[l]), 0.f);
    atomicAdd(&pool[batch[i] * 64 + l], h2);
}

// per-graph head: tabular MLP + mean pool + fusion MLP. 64 threads per graph.
// graph node count via binary search on sorted batch (no atomics).
__global__ void __launch_bounds__(64) k_head(const float* tabular,
        const float* Wt1, const float* bt1, const float* Wt2, const float* bt2,
        const float* Wf1, const float* bf1, const float* Wf2, const float* bf2,
        const float* pool, const int* batch, float* out, int TD, int N) {
    __shared__ float tl[128];
    __shared__ float t1[64];
    __shared__ float comb[128];
    __shared__ float f1[64];
    __shared__ float cnts;
    int g = blockIdx.x, l = threadIdx.x;
    if (l == 0) {
        int lo = 0, hi = N;
        while (lo < hi) { int m = (lo + hi) >> 1; if (batch[m] < g) lo = m + 1; else hi = m; }
        int lo2 = lo, hi2 = N;
        while (lo2 < hi2) { int m = (lo2 + hi2) >> 1; if (batch[m] <= g) lo2 = m + 1; else hi2 = m; }
        int c = lo2 - lo;
        cnts = (float)(c > 1 ? c : 1);
    }
    for (int k = l; k < TD; k += 64) tl[k] = tabular[g * TD + k];
    __syncthreads();
    float a = bt1[l];
    for (int k = 0; k < TD; ++k) a += tl[k] * Wt1[k * 64 + l];
    t1[l] = a > 0.f ? a : 0.f;
    __syncthreads();
    float b = bt2[l];
    #pragma unroll
    for (int k = 0; k < 64; ++k) b += t1[k] * Wt2[k * 64 + l];
    comb[l] = b;
    comb[64 + l] = pool[g * 64 + l] / cnts;
    __syncthreads();
    float f = bf1[l];
    for (int k = 0; k < 128; ++k) f += comb[k] * Wf1[k * 64 + l];
    f1[l] = f > 0.f ? f : 0.f;
    __syncthreads();
    if (l < 2) {
        float o = bf2[l];
        #pragma unroll
        for (int k = 0; k < 64; ++k) o += f1[k] * Wf2[k * 2 + l];
        out[g * 2 + l] = o;
    }
}

// ---------------- launcher ----------------

extern "C" void kernel_launch(void* const* d_in, const int* in_sizes, int n_in,
                              void* d_out, int out_size, void* d_ws, size_t ws_size,
                              hipStream_t stream) {
    const float* tabular = (const float*)d_in[0];
    const float* x       = (const float*)d_in[1];
    const int*   ei      = (const int*)d_in[2];
    const int*   batch   = (const int*)d_in[3];
    const float* Wt1 = (const float*)d_in[4];
    const float* bt1 = (const float*)d_in[5];
    const float* Wt2 = (const float*)d_in[6];
    const float* bt2 = (const float*)d_in[7];
    const float* Wg1 = (const float*)d_in[8];
    const float* bg1 = (const float*)d_in[9];
    const float* Wg2 = (const float*)d_in[10];
    const float* bg2 = (const float*)d_in[11];
    const float* Wf1 = (const float*)d_in[12];
    const float* bf1 = (const float*)d_in[13];
    const float* Wf2 = (const float*)d_in[14];
    const float* bf2 = (const float*)d_in[15];

    const int N  = in_sizes[1];
    const int E  = in_sizes[2] / 2;
    const int H  = in_sizes[5];             // 64
    const int TD = in_sizes[4] / H;         // 128
    const int B  = in_sizes[0] / TD;        // 1024
    const int EL = E + N;

    // workspace layout
    char* w = (char*)d_ws;
    size_t off = 0;
    auto alloc = [&](size_t bytes) -> void* {
        void* p = w + off;
        off = (off + bytes + 255) & ~(size_t)255;
        return p;
    };
    int*   cnt  = (int*)alloc((size_t)N * 4);
    int*   offs = (int*)alloc((size_t)(N + 1) * 4);
    int*   cur  = (int*)alloc((size_t)N * 4);
    int*   bsum = (int*)alloc(1024);
    int*   boff = (int*)alloc(1024);
    float* dis  = (float*)alloc((size_t)N * 4);
    float* dx   = (float*)alloc((size_t)N * 4);
    float* s1   = (float*)alloc((size_t)N * 4);
    int*   csr  = (int*)alloc((size_t)EL * 4);
    __hip_bfloat16* hw1b = (__hip_bfloat16*)alloc((size_t)N * 64 * 2);
    float* pool = (float*)alloc((size_t)B * 64 * 4);
    (void)ws_size;

    hipMemsetAsync(cnt, 0, (size_t)N * 4, stream);
    hipMemsetAsync(pool, 0, (size_t)B * 64 * 4, stream);

    const int nblk_scan = (N + 1023) / 1024;   // 196 for N=200000 (<=256 ok)

    k_hist<<<(E + 255) / 256, 256, 0, stream>>>(ei + E, cnt, E);
    k_scan1<<<nblk_scan, 256, 0, stream>>>(cnt, offs, bsum, N);
    k_scan2<<<1, 256, 0, stream>>>(bsum, boff, nblk_scan);
    k_scan3<<<(N + 255) / 256, 256, 0, stream>>>(offs, boff, cur, cnt, x, dis, dx, N, EL);
    k_fill<<<(EL + 255) / 256, 256, 0, stream>>>(ei, cur, csr, E, N);
    k_agg1<<<(N + 255) / 256, 256, 0, stream>>>(offs, csr, dx, dis, s1, N);
    k_hw1<<<(N + 15) / 16, 256, 0, stream>>>(s1, dis, Wg1, bg1, Wg2, hw1b, N);
    k_agg2<<<(N + 3) / 4, 256, 0, stream>>>(offs, csr, hw1b, dis, bg2, batch, pool, N);
    k_head<<<B, 64, 0, stream>>>(tabular, Wt1, bt1, Wt2, bt2,
                                 Wf1, bf1, Wf2, bf2, pool, batch,
                                 (float*)d_out, TD, N);
}